// Round 6
// baseline (343.097 us; speedup 1.0000x reference)
//
#include <hip/hip_runtime.h>
#include <hip/hip_bf16.h>
#include <hip/hip_fp16.h>

#define DD    128
#define VOCAB 2048
#define NRELS 7
#define NWF   (130 * 16384)   // W frag-layout elements: 128 kron + l + r chunks

typedef _Float16 f16;
typedef __attribute__((ext_vector_type(8))) _Float16 f16x8;
typedef __attribute__((ext_vector_type(4))) float    f32x4;

// flexible-dtype load: bf==1 -> bf16 storage, bf==0 -> f32 storage
__device__ __forceinline__ float lde(const void* p, size_t i, int bf) {
    if (bf) return (float)((const __hip_bfloat16*)p)[i];
    return ((const float*)p)[i];
}

// detect storage dtype by exponent-field sanity of Wv's first 64 uint16s
__device__ __forceinline__ int detect_bf(const unsigned short* wv) {
    int sane = 0;
    #pragma unroll
    for (int i = 0; i < 64; ++i) {
        unsigned e = (wv[i] >> 7) & 0xFFu;
        sane += (e >= 90u && e <= 160u) ? 1 : 0;
    }
    return sane == 64;
}

// ---------------------------------------------------------------------------
// prep_all: one launch does everything.
//  b <  64        : WvT[v][d] = Wv[d][v] + bv[d]  (64x64 LDS transpose tiles)
//  64 <= b < 2144 : W frag-major repack (which, i, n8), see below
//  b == 2144      : biases + Wsm/bsm f32 copies
// Frag layout: Wf[((i*8+n8)*4+t)*512 + ln*8 + e] =
//              W[n8*16+(ln&15)][i*128 + t*32 + (ln>>4)*8 + e]
// ---------------------------------------------------------------------------
__global__ void prep_all(const void* Wv, const void* bv,
                         const void* Wcps, const void* bcps,
                         const void* Wcpst, const void* bcpst,
                         const void* Wcpr, const void* bcpr,
                         const void* Wcprt, const void* bcprt,
                         const void* Wsm, const void* bsm,
                         f16* __restrict__ WvT, f16* __restrict__ Wext, f16* __restrict__ Wfin,
                         float* __restrict__ bias_lvl, float* __restrict__ bias_fin,
                         float* __restrict__ Wsm_f, float* __restrict__ bsm_f)
{
    const int bf = detect_bf((const unsigned short*)Wv);
    const int b = blockIdx.x;
    const int tid = threadIdx.x;

    if (b < 64) {                     // ---- WvT transpose ----
        __shared__ float tile[64][65];
        int vt = b >> 1, dt = b & 1;
        int tx = tid & 63, ty = tid >> 6;
        for (int yy = ty; yy < 64; yy += 4)
            tile[yy][tx] = lde(Wv, (size_t)(dt * 64 + yy) * VOCAB + vt * 64 + tx, bf);
        __syncthreads();
        for (int yy = ty; yy < 64; yy += 4) {
            int v = vt * 64 + yy, d = dt * 64 + tx;
            WvT[(size_t)v * DD + d] = (f16)(tile[tx][yy] + lde(bv, d, bf));
        }
        return;
    }
    if (b >= 2144) {                  // ---- biases + softmax weights ----
        if (tid < 128)      bias_lvl[tid] = lde(bcps, tid, bf) + lde(bcpst, tid, bf);
        else if (tid < 256) bias_fin[tid - 128] = lde(bcpr, tid - 128, bf) + lde(bcprt, tid - 128, bf);
        for (int o = tid; o < NRELS * DD; o += 256) Wsm_f[o] = lde(Wsm, o, bf);
        if (tid < NRELS) bsm_f[tid] = lde(bsm, tid, bf);
        return;
    }
    // ---- W frag repack ----
    const int bb    = b - 64;
    const int which = bb / 1040;      // 0: ext, 1: fin
    const int rem   = bb - which * 1040;
    const int i     = rem >> 3;       // 0..129
    const int n8    = rem & 7;
    const void* Wt = which ? (const void*)Wcprt : (const void*)Wcpst;
    const void* Ws = which ? (const void*)Wcpr  : (const void*)Wcps;
    f16* dst = which ? Wfin : Wext;

    __shared__ float tile[16 * 129];
    #pragma unroll
    for (int it = 0; it < 8; ++it) {
        int idx = it * 256 + tid;
        int rr = idx >> 7, c = idx & 127;
        float v = (i < 128) ? lde(Wt, (size_t)(n8 * 16 + rr) * 16384 + (size_t)i * 128 + c, bf)
                            : lde(Ws, (size_t)(n8 * 16 + rr) * 256 + (size_t)(i - 128) * 128 + c, bf);
        tile[rr * 129 + c] = v;
    }
    __syncthreads();
    f16* out = dst + (size_t)(i * 8 + n8) * 2048;
    #pragma unroll
    for (int it = 0; it < 8; ++it) {
        int o = it * 256 + tid;
        int t = o >> 9, ln = (o >> 3) & 63, e = o & 7;
        out[o] = (f16)tile[(ln & 15) * 129 + t * 32 + ((ln >> 4) << 3) + e];
    }
}

// ---------------------------------------------------------------------------
// GEMM over A_ext = [kron(l,r) | l | r] vs W (128 x 16640), split-K over kron
// rows i. Block = 128 merge-rows x 64 n (one n-half), 2 waves stacked on rows
// reading IDENTICAL W fragments (L1 reuse). XCD-pinned n-half (nh=(b>>2)&1).
// 4-deep register prefetch ring for W (no K-loop barriers). If ids != null,
// gather input rows from hin (=WvT) via leaf ids (fused embedding).
// s==1 appends lin-l (i=128), s==2 lin-r (i=129). Partials f16.
// ---------------------------------------------------------------------------
__launch_bounds__(128, 2)
__global__ void gemm_kernel(const f16* __restrict__ hin, const int* __restrict__ ids,
                            const f16* __restrict__ Wf,
                            f16* __restrict__ part, int Mrows, int S, int BI)
{
    __shared__ f16 Lt[128 * 128];       // 32 KB, phys 8-half block = cb ^ (row&15)

    const int tid  = threadIdx.x;
    const int lane = tid & 63;
    const int wv   = tid >> 6;
    const int b    = blockIdx.x;
    const int nh   = (b >> 2) & 1;                 // XCD-half -> n-half
    const int r    = ((b >> 3) << 2) | (b & 3);    // 0 .. grid/2-1
    const int mb   = r / S;
    const int s    = r - mb * S;
    const int m0   = mb * 128;
    const int i0   = s * BI;
    const int nI   = BI + ((s == 1 || s == 2) ? 1 : 0);
    const int NSt  = nI * 4;

    // ---- stage Lt (l rows), swizzled 8-half blocks ----
    #pragma unroll
    for (int it = 0; it < 16; ++it) {
        int c  = it * 128 + tid;            // 0..2047
        int mm = c >> 4;                    // 0..127
        int cb = c & 15;
        int row = ids ? ids[2 * (m0 + mm)] : 2 * (m0 + mm);
        f16x8 v = *(const f16x8*)&hin[(size_t)row * DD + cb * 8];
        *(f16x8*)&Lt[mm * 128 + ((cb ^ (mm & 15)) << 3)] = v;
    }

    const int mrow = lane & 15;
    const int q    = lane >> 4;
    const int wm   = wv * 64;

    // ---- r fragments for this wave's 64 rows (reused across all i) ----
    f16x8 rf[4][4];
    #pragma unroll
    for (int mt = 0; mt < 4; ++mt) {
        int p = m0 + wm + mt * 16 + mrow;
        int row = ids ? ids[2 * p + 1] : 2 * p + 1;
        #pragma unroll
        for (int t = 0; t < 4; ++t)
            rf[mt][t] = *(const f16x8*)&hin[(size_t)row * DD + t * 32 + q * 8];
    }

    __syncthreads();

    auto imap = [&](int ii) { return (ii < BI) ? (i0 + ii) : (s == 1 ? 128 : 129); };
    const f16* wb0 = Wf + nh * 8192 + lane * 8;
    auto ldW = [&](int ic, int tt, f16x8* d) {
        const f16* p = wb0 + (size_t)imap(ic) * 16384 + tt * 512;
        #pragma unroll
        for (int nt = 0; nt < 4; ++nt) d[nt] = *(const f16x8*)(p + nt * 2048);
    };
    auto lpRead = [&](int i, int mt) -> f16 {
        return Lt[(wm + mt * 16 + mrow) * 128 + (((i >> 3) ^ mrow) << 3) + (i & 7)];
    };

    f32x4 acc[4][4] = {};
    f16x8 wbuf[4][4];                   // 4-deep prefetch ring
    f16 lpv[4], lpn[4];

    ldW(0, 0, wbuf[0]);
    ldW(0, 1, wbuf[1]);
    ldW(0, 2, wbuf[2]);
    {
        int i = imap(0);
        if (i < 128) {
            #pragma unroll
            for (int mt = 0; mt < 4; ++mt) lpv[mt] = lpRead(i, mt);
        }
    }

#define TSTEP(T) {                                                                      \
    const f16x8* wc = wbuf[T];                                                          \
    if (i < 128) {                                                                      \
        _Pragma("unroll")                                                               \
        for (int mt = 0; mt < 4; ++mt) {                                                \
            f16x8 a = lb[mt] * rf[mt][T];                                               \
            _Pragma("unroll")                                                           \
            for (int nt = 0; nt < 4; ++nt)                                              \
                acc[mt][nt] = __builtin_amdgcn_mfma_f32_16x16x32_f16(a, wc[nt], acc[mt][nt], 0, 0, 0); \
        }                                                                               \
    } else if (i == 128) {                                                              \
        _Pragma("unroll")                                                               \
        for (int mt = 0; mt < 4; ++mt) {                                                \
            f16x8 a = *(const f16x8*)&Lt[(wm + mt * 16 + mrow) * 128 + ((((T) * 4 + q) ^ mrow) << 3)]; \
            _Pragma("unroll")                                                           \
            for (int nt = 0; nt < 4; ++nt)                                              \
                acc[mt][nt] = __builtin_amdgcn_mfma_f32_16x16x32_f16(a, wc[nt], acc[mt][nt], 0, 0, 0); \
        }                                                                               \
    } else {                                                                            \
        _Pragma("unroll")                                                               \
        for (int mt = 0; mt < 4; ++mt) {                                                \
            _Pragma("unroll")                                                           \
            for (int nt = 0; nt < 4; ++nt)                                              \
                acc[mt][nt] = __builtin_amdgcn_mfma_f32_16x16x32_f16(rf[mt][T], wc[nt], acc[mt][nt], 0, 0, 0); \
        }                                                                               \
    } }

    for (int ii = 0; ii < nI; ++ii) {
        const int i = imap(ii);
        const bool more = (ii + 1 < nI);
        f16x8 lb[4];
        if (i < 128) {
            #pragma unroll
            for (int mt = 0; mt < 4; ++mt) {
                f16 v = lpv[mt];
                #pragma unroll
                for (int e = 0; e < 8; ++e) lb[mt][e] = v;
            }
        }
        // t = 0 : prefetch (ii, t=3) -> slot 3
        ldW(ii, 3, wbuf[3]);
        TSTEP(0);
        // t = 1 : prefetch (ii+1, t=0) -> slot 0 ; Lt broadcast prefetch
        if (more) {
            ldW(ii + 1, 0, wbuf[0]);
            int i2 = imap(ii + 1);
            if (i2 < 128) {
                #pragma unroll
                for (int mt = 0; mt < 4; ++mt) lpn[mt] = lpRead(i2, mt);
            }
        }
        TSTEP(1);
        // t = 2 : prefetch (ii+1, t=1) -> slot 1
        if (more) ldW(ii + 1, 1, wbuf[1]);
        TSTEP(2);
        // t = 3 : prefetch (ii+1, t=2) -> slot 2
        if (more) ldW(ii + 1, 2, wbuf[2]);
        TSTEP(3);
        #pragma unroll
        for (int mt = 0; mt < 4; ++mt) lpv[mt] = lpn[mt];
    }
#undef TSTEP

    // ---- store f16 partial tile: C/D layout col=lane&15, row=q*4+reg ----
    f16* pb = part + ((size_t)s * Mrows + m0) * DD + nh * 64;
    #pragma unroll
    for (int mt = 0; mt < 4; ++mt)
        #pragma unroll
        for (int nt = 0; nt < 4; ++nt) {
            int colg = nt * 16 + mrow;
            #pragma unroll
            for (int rr = 0; rr < 4; ++rr) {
                int rowl = wm + mt * 16 + q * 4 + rr;
                pb[(size_t)rowl * DD + colg] = (f16)acc[mt][nt][rr];
            }
        }
}

// ---------------------------------------------------------------------------
// level epilogue: h_out = f16(tanh(sum_s part[s] + bias))
// ---------------------------------------------------------------------------
__global__ void epi_level(const f16* __restrict__ part, const float* __restrict__ bias,
                          f16* __restrict__ hout, int Mrows, int S)
{
    int idx = (blockIdx.x * 256 + threadIdx.x) * 8;
    size_t stride = (size_t)Mrows * DD;
    float sum[8] = {};
    for (int s2 = 0; s2 < S; ++s2) {
        f16x8 v = *(const f16x8*)&part[(size_t)s2 * stride + idx];
        #pragma unroll
        for (int e = 0; e < 8; ++e) sum[e] += (float)v[e];
    }
    int n = idx & 127;
    f16x8 o;
    #pragma unroll
    for (int e = 0; e < 8; ++e) o[e] = (f16)tanhf(sum[e] + bias[n + e]);
    *(f16x8*)&hout[idx] = o;
}

// ---------------------------------------------------------------------------
// final epilogue: leaky_relu(sum_s part + bias) @ Wsm^T + bsm -> log_softmax
// ---------------------------------------------------------------------------
__global__ void fin_epi(const f16* __restrict__ part, const float* __restrict__ bias,
                        const float* __restrict__ Wsm_f, const float* __restrict__ bsm_f,
                        const unsigned short* __restrict__ wv_raw, void* __restrict__ outp, int S)
{
    int lane = threadIdx.x & 63;
    int wv = threadIdx.x >> 6;
    int p = blockIdx.x * 4 + wv;              // 0..511
    size_t stride = (size_t)512 * DD;
    const f16* base = part + (size_t)p * DD;
    float a0 = 0.f, a1 = 0.f;
    for (int s2 = 0; s2 < S; ++s2) {
        a0 += (float)base[(size_t)s2 * stride + lane];
        a1 += (float)base[(size_t)s2 * stride + 64 + lane];
    }
    a0 += bias[lane];      a1 += bias[64 + lane];
    a0 = (a0 > 0.f) ? a0 : 0.01f * a0;
    a1 = (a1 > 0.f) ? a1 : 0.01f * a1;
    float lg[NRELS];
    #pragma unroll
    for (int r = 0; r < NRELS; ++r) {
        float pr = a0 * Wsm_f[r * DD + lane] + a1 * Wsm_f[r * DD + 64 + lane];
        #pragma unroll
        for (int d = 1; d < 64; d <<= 1) pr += __shfl_xor(pr, d, 64);
        lg[r] = pr + bsm_f[r];
    }
    float mx = lg[0];
    #pragma unroll
    for (int r = 1; r < NRELS; ++r) mx = fmaxf(mx, lg[r]);
    float se = 0.f;
    #pragma unroll
    for (int r = 0; r < NRELS; ++r) se += expf(lg[r] - mx);
    float lse = logf(se) + mx;
    if (lane < NRELS) {
        float v = lg[lane] - lse;
        if (detect_bf(wv_raw)) ((__hip_bfloat16*)outp)[p * NRELS + lane] = __float2bfloat16(v);
        else                   ((float*)outp)[p * NRELS + lane] = v;
    }
}

// ---------------------------------------------------------------------------
extern "C" void kernel_launch(void* const* d_in, const int* in_sizes, int n_in,
                              void* d_out, int out_size, void* d_ws, size_t ws_size,
                              hipStream_t stream)
{
    const int* ids = (const int*)d_in[0];

    char* ws = (char*)d_ws;
    f16*   part     = (f16*)ws;                                      // 16 MiB region (f16 partials)
    f16*   h1       = (f16*)(ws + ((size_t)20 << 20));               // 2 MiB
    f16*   h2       = (f16*)(ws + ((size_t)22 << 20));               // 1 MiB
    f16*   h3       = (f16*)(ws + ((size_t)23 << 20));               // 0.5 MiB
    f16*   h4       = (f16*)(ws + ((size_t)23 << 20) + (512 << 10)); // 0.25 MiB
    f16*   WvT      = (f16*)(ws + ((size_t)24 << 20));               // 0.5 MiB
    f16*   Wext     = (f16*)(ws + ((size_t)24 << 20) + (512 << 10)); // 4.0625 MiB
    f16*   Wfin     = Wext + (size_t)NWF;                            // 4.0625 MiB
    float* bias_lvl = (float*)(Wfin + (size_t)NWF);
    float* bias_fin = bias_lvl + 128;
    float* Wsm_f    = bias_fin + 128;
    float* bsm_f    = Wsm_f + NRELS * DD;

    if (ws_size < ((size_t)34 << 20)) return;

    prep_all<<<2145, 256, 0, stream>>>(d_in[1], d_in[2], d_in[3], d_in[4], d_in[5], d_in[6],
                                       d_in[7], d_in[8], d_in[9], d_in[10], d_in[11], d_in[12],
                                       WvT, Wext, Wfin, bias_lvl, bias_fin, Wsm_f, bsm_f);

    // level 1 (fused embed-gather): M=8192, 64 tiles x S=8 x 2 nh -> 1024
    gemm_kernel<<<1024, 128, 0, stream>>>(WvT, ids, Wext, part, 8192, 8, 16);
    epi_level<<<512, 256, 0, stream>>>(part, bias_lvl, h1, 8192, 8);
    // level 2: M=4096, 32 x S=16 x 2 -> 1024
    gemm_kernel<<<1024, 128, 0, stream>>>(h1, nullptr, Wext, part, 4096, 16, 8);
    epi_level<<<256, 256, 0, stream>>>(part, bias_lvl, h2, 4096, 16);
    // level 3: M=2048, 16 x S=32 x 2 -> 1024
    gemm_kernel<<<1024, 128, 0, stream>>>(h2, nullptr, Wext, part, 2048, 32, 4);
    epi_level<<<128, 256, 0, stream>>>(part, bias_lvl, h3, 2048, 32);
    // level 4: M=1024, 8 x S=32 x 2 -> 512
    gemm_kernel<<<512, 128, 0, stream>>>(h3, nullptr, Wext, part, 1024, 32, 4);
    epi_level<<<64, 256, 0, stream>>>(part, bias_lvl, h4, 1024, 32);
    // final: M=512, 4 x S=64 x 2 -> 512
    gemm_kernel<<<512, 128, 0, stream>>>(h4, nullptr, Wfin, part, 512, 64, 2);
    fin_epi<<<128, 256, 0, stream>>>(part, bias_fin, Wsm_f, bsm_f,
                                     (const unsigned short*)d_in[1], d_out, 64);
}

// Round 7
// 284.171 us; speedup vs baseline: 1.2074x; 1.2074x over previous
//
#include <hip/hip_runtime.h>
#include <hip/hip_bf16.h>
#include <hip/hip_fp16.h>

#define DD    128
#define VOCAB 2048
#define NRELS 7
#define NWF   (130 * 16384)   // W frag-layout elements: 128 kron + l + r chunks

typedef _Float16 f16;
typedef __attribute__((ext_vector_type(8))) _Float16 f16x8;
typedef __attribute__((ext_vector_type(4))) float    f32x4;

// flexible-dtype load: bf==1 -> bf16 storage, bf==0 -> f32 storage
__device__ __forceinline__ float lde(const void* p, size_t i, int bf) {
    if (bf) return (float)((const __hip_bfloat16*)p)[i];
    return ((const float*)p)[i];
}

// detect storage dtype by exponent-field sanity of Wv's first 64 uint16s
__device__ __forceinline__ int detect_bf(const unsigned short* wv) {
    int sane = 0;
    #pragma unroll
    for (int i = 0; i < 64; ++i) {
        unsigned e = (wv[i] >> 7) & 0xFFu;
        sane += (e >= 90u && e <= 160u) ? 1 : 0;
    }
    return sane == 64;
}

// ---------------------------------------------------------------------------
// prep_all: one launch does everything.
//  b <  64        : WvT[v][d] = Wv[d][v] + bv[d]  (64x64 LDS transpose tiles)
//  64 <= b < 2144 : W frag-major repack (which, i, n8)
//  b == 2144      : biases + Wsm/bsm f32 copies
// Frag layout: Wf[((i*8+n8)*4+t)*512 + ln*8 + e] =
//              W[n8*16+(ln&15)][i*128 + t*32 + (ln>>4)*8 + e]
// ---------------------------------------------------------------------------
__global__ void prep_all(const void* Wv, const void* bv,
                         const void* Wcps, const void* bcps,
                         const void* Wcpst, const void* bcpst,
                         const void* Wcpr, const void* bcpr,
                         const void* Wcprt, const void* bcprt,
                         const void* Wsm, const void* bsm,
                         f16* __restrict__ WvT, f16* __restrict__ Wext, f16* __restrict__ Wfin,
                         float* __restrict__ bias_lvl, float* __restrict__ bias_fin,
                         float* __restrict__ Wsm_f, float* __restrict__ bsm_f)
{
    const int bf = detect_bf((const unsigned short*)Wv);
    const int b = blockIdx.x;
    const int tid = threadIdx.x;

    if (b < 64) {                     // ---- WvT transpose ----
        __shared__ float tile[64][65];
        int vt = b >> 1, dt = b & 1;
        int tx = tid & 63, ty = tid >> 6;
        for (int yy = ty; yy < 64; yy += 4)
            tile[yy][tx] = lde(Wv, (size_t)(dt * 64 + yy) * VOCAB + vt * 64 + tx, bf);
        __syncthreads();
        for (int yy = ty; yy < 64; yy += 4) {
            int v = vt * 64 + yy, d = dt * 64 + tx;
            WvT[(size_t)v * DD + d] = (f16)(tile[tx][yy] + lde(bv, d, bf));
        }
        return;
    }
    if (b >= 2144) {                  // ---- biases + softmax weights ----
        if (tid < 128)      bias_lvl[tid] = lde(bcps, tid, bf) + lde(bcpst, tid, bf);
        else if (tid < 256) bias_fin[tid - 128] = lde(bcpr, tid - 128, bf) + lde(bcprt, tid - 128, bf);
        for (int o = tid; o < NRELS * DD; o += 256) Wsm_f[o] = lde(Wsm, o, bf);
        if (tid < NRELS) bsm_f[tid] = lde(bsm, tid, bf);
        return;
    }
    // ---- W frag repack ----
    const int bb    = b - 64;
    const int which = bb / 1040;      // 0: ext, 1: fin
    const int rem   = bb - which * 1040;
    const int i     = rem >> 3;       // 0..129
    const int n8    = rem & 7;
    const void* Wt = which ? (const void*)Wcprt : (const void*)Wcpst;
    const void* Ws = which ? (const void*)Wcpr  : (const void*)Wcps;
    f16* dst = which ? Wfin : Wext;

    __shared__ float tile[16 * 129];
    #pragma unroll
    for (int it = 0; it < 8; ++it) {
        int idx = it * 256 + tid;
        int rr = idx >> 7, c = idx & 127;
        float v = (i < 128) ? lde(Wt, (size_t)(n8 * 16 + rr) * 16384 + (size_t)i * 128 + c, bf)
                            : lde(Ws, (size_t)(n8 * 16 + rr) * 256 + (size_t)(i - 128) * 128 + c, bf);
        tile[rr * 129 + c] = v;
    }
    __syncthreads();
    f16* out = dst + (size_t)(i * 8 + n8) * 2048;
    #pragma unroll
    for (int it = 0; it < 8; ++it) {
        int o = it * 256 + tid;
        int t = o >> 9, ln = (o >> 3) & 63, e = o & 7;
        out[o] = (f16)tile[(ln & 15) * 129 + t * 32 + ((ln >> 4) << 3) + e];
    }
}

// ---------------------------------------------------------------------------
// GEMM over A_ext = [kron(l,r) | l | r] vs W (128 x 16640), split-K over kron
// rows i. Block = 128 merge-rows x 64 n (one n-half), 2 waves stacked on rows
// reading IDENTICAL W fragments (L1 reuse). XCD-pinned n-half (nh=(b>>2)&1).
// W prefetch: 2-slot ring, each slot REFILLED right after its consumer TSTEP
// -> every load issued 2 stages before use, waits are fine-grained vmcnt(4),
// never a full drain, and register pressure equals the no-spill R5 kernel.
// If ids != null, gather input rows from hin (=WvT) via leaf ids.
// s==1 appends lin-l (i=128), s==2 lin-r (i=129). Partials f16.
// ---------------------------------------------------------------------------
__launch_bounds__(128, 2)
__global__ void gemm_kernel(const f16* __restrict__ hin, const int* __restrict__ ids,
                            const f16* __restrict__ Wf,
                            f16* __restrict__ part, int Mrows, int S, int BI)
{
    __shared__ f16 Lt[128 * 128];       // 32 KB, phys 8-half block = cb ^ (row&15)

    const int tid  = threadIdx.x;
    const int lane = tid & 63;
    const int wv   = tid >> 6;
    const int b    = blockIdx.x;
    const int nh   = (b >> 2) & 1;                 // XCD-half -> n-half
    const int r    = ((b >> 3) << 2) | (b & 3);    // 0 .. grid/2-1
    const int mb   = r / S;
    const int s    = r - mb * S;
    const int m0   = mb * 128;
    const int i0   = s * BI;
    const int nI   = BI + ((s == 1 || s == 2) ? 1 : 0);

    // ---- stage Lt (l rows), swizzled 8-half blocks ----
    #pragma unroll
    for (int it = 0; it < 16; ++it) {
        int c  = it * 128 + tid;            // 0..2047
        int mm = c >> 4;                    // 0..127
        int cb = c & 15;
        int row = ids ? ids[2 * (m0 + mm)] : 2 * (m0 + mm);
        f16x8 v = *(const f16x8*)&hin[(size_t)row * DD + cb * 8];
        *(f16x8*)&Lt[mm * 128 + ((cb ^ (mm & 15)) << 3)] = v;
    }

    const int mrow = lane & 15;
    const int q    = lane >> 4;
    const int wm   = wv * 64;

    // ---- r fragments for this wave's 64 rows (reused across all i) ----
    f16x8 rf[4][4];
    #pragma unroll
    for (int mt = 0; mt < 4; ++mt) {
        int p = m0 + wm + mt * 16 + mrow;
        int row = ids ? ids[2 * p + 1] : 2 * p + 1;
        #pragma unroll
        for (int t = 0; t < 4; ++t)
            rf[mt][t] = *(const f16x8*)&hin[(size_t)row * DD + t * 32 + q * 8];
    }

    __syncthreads();

    auto imap = [&](int ii) { return (ii < BI) ? (i0 + ii) : (s == 1 ? 128 : 129); };
    const f16* wb0 = Wf + nh * 8192 + lane * 8;
    auto ldW = [&](int ic, int tt, f16x8* d) {
        const f16* p = wb0 + (size_t)imap(ic) * 16384 + tt * 512;
        #pragma unroll
        for (int nt = 0; nt < 4; ++nt) d[nt] = *(const f16x8*)(p + nt * 2048);
    };
    auto lpRead = [&](int i, int mt) -> f16 {
        return Lt[(wm + mt * 16 + mrow) * 128 + (((i >> 3) ^ mrow) << 3) + (i & 7)];
    };

    f32x4 acc[4][4] = {};
    f16x8 wbuf[2][4];                   // 2-slot ring, depth-2 via post-use refill
    f16 lpv[4], lpn[4];

    ldW(0, 0, wbuf[0]);                 // slot0 = (ii=0, t=0)
    ldW(0, 1, wbuf[1]);                 // slot1 = (ii=0, t=1)
    {
        int i = imap(0);
        if (i < 128) {
            #pragma unroll
            for (int mt = 0; mt < 4; ++mt) lpv[mt] = lpRead(i, mt);
        }
    }

#define TSTEP(T) {                                                                      \
    const f16x8* wc = wbuf[(T) & 1];                                                    \
    if (i < 128) {                                                                      \
        _Pragma("unroll")                                                               \
        for (int mt = 0; mt < 4; ++mt) {                                                \
            f16x8 a = lb[mt] * rf[mt][T];                                               \
            _Pragma("unroll")                                                           \
            for (int nt = 0; nt < 4; ++nt)                                              \
                acc[mt][nt] = __builtin_amdgcn_mfma_f32_16x16x32_f16(a, wc[nt], acc[mt][nt], 0, 0, 0); \
        }                                                                               \
    } else if (i == 128) {                                                              \
        _Pragma("unroll")                                                               \
        for (int mt = 0; mt < 4; ++mt) {                                                \
            f16x8 a = *(const f16x8*)&Lt[(wm + mt * 16 + mrow) * 128 + ((((T) * 4 + q) ^ mrow) << 3)]; \
            _Pragma("unroll")                                                           \
            for (int nt = 0; nt < 4; ++nt)                                              \
                acc[mt][nt] = __builtin_amdgcn_mfma_f32_16x16x32_f16(a, wc[nt], acc[mt][nt], 0, 0, 0); \
        }                                                                               \
    } else {                                                                            \
        _Pragma("unroll")                                                               \
        for (int mt = 0; mt < 4; ++mt) {                                                \
            _Pragma("unroll")                                                           \
            for (int nt = 0; nt < 4; ++nt)                                              \
                acc[mt][nt] = __builtin_amdgcn_mfma_f32_16x16x32_f16(rf[mt][T], wc[nt], acc[mt][nt], 0, 0, 0); \
        }                                                                               \
    } }

    for (int ii = 0; ii < nI; ++ii) {
        const int i = imap(ii);
        const bool more = (ii + 1 < nI);
        f16x8 lb[4];
        if (i < 128) {
            #pragma unroll
            for (int mt = 0; mt < 4; ++mt) {
                f16 v = lpv[mt];
                #pragma unroll
                for (int e = 0; e < 8; ++e) lb[mt][e] = v;
            }
        }
        TSTEP(0);                       // uses slot0 = (ii,0)
        ldW(ii, 2, wbuf[0]);            // refill slot0 with (ii,2)
        TSTEP(1);                       // uses slot1 = (ii,1)
        ldW(ii, 3, wbuf[1]);            // refill slot1 with (ii,3)
        if (more) {
            int i2 = imap(ii + 1);
            if (i2 < 128) {
                #pragma unroll
                for (int mt = 0; mt < 4; ++mt) lpn[mt] = lpRead(i2, mt);
            }
        }
        TSTEP(2);                       // uses slot0 = (ii,2)
        if (more) ldW(ii + 1, 0, wbuf[0]);   // refill slot0 with (ii+1,0)
        TSTEP(3);                       // uses slot1 = (ii,3)
        if (more) ldW(ii + 1, 1, wbuf[1]);   // refill slot1 with (ii+1,1)
        #pragma unroll
        for (int mt = 0; mt < 4; ++mt) lpv[mt] = lpn[mt];
    }
#undef TSTEP

    // ---- store f16 partial tile: C/D layout col=lane&15, row=q*4+reg ----
    f16* pb = part + ((size_t)s * Mrows + m0) * DD + nh * 64;
    #pragma unroll
    for (int mt = 0; mt < 4; ++mt)
        #pragma unroll
        for (int nt = 0; nt < 4; ++nt) {
            int colg = nt * 16 + mrow;
            #pragma unroll
            for (int rr = 0; rr < 4; ++rr) {
                int rowl = wm + mt * 16 + q * 4 + rr;
                pb[(size_t)rowl * DD + colg] = (f16)acc[mt][nt][rr];
            }
        }
}

// ---------------------------------------------------------------------------
// level epilogue: h_out = f16(tanh(sum_s part[s] + bias))
// ---------------------------------------------------------------------------
__global__ void epi_level(const f16* __restrict__ part, const float* __restrict__ bias,
                          f16* __restrict__ hout, int Mrows, int S)
{
    int idx = (blockIdx.x * 256 + threadIdx.x) * 8;
    size_t stride = (size_t)Mrows * DD;
    float sum[8] = {};
    for (int s2 = 0; s2 < S; ++s2) {
        f16x8 v = *(const f16x8*)&part[(size_t)s2 * stride + idx];
        #pragma unroll
        for (int e = 0; e < 8; ++e) sum[e] += (float)v[e];
    }
    int n = idx & 127;
    f16x8 o;
    #pragma unroll
    for (int e = 0; e < 8; ++e) o[e] = (f16)tanhf(sum[e] + bias[n + e]);
    *(f16x8*)&hout[idx] = o;
}

// ---------------------------------------------------------------------------
// final epilogue: leaky_relu(sum_s part + bias) @ Wsm^T + bsm -> log_softmax
// ---------------------------------------------------------------------------
__global__ void fin_epi(const f16* __restrict__ part, const float* __restrict__ bias,
                        const float* __restrict__ Wsm_f, const float* __restrict__ bsm_f,
                        const unsigned short* __restrict__ wv_raw, void* __restrict__ outp, int S)
{
    int lane = threadIdx.x & 63;
    int wv = threadIdx.x >> 6;
    int p = blockIdx.x * 4 + wv;              // 0..511
    size_t stride = (size_t)512 * DD;
    const f16* base = part + (size_t)p * DD;
    float a0 = 0.f, a1 = 0.f;
    for (int s2 = 0; s2 < S; ++s2) {
        a0 += (float)base[(size_t)s2 * stride + lane];
        a1 += (float)base[(size_t)s2 * stride + 64 + lane];
    }
    a0 += bias[lane];      a1 += bias[64 + lane];
    a0 = (a0 > 0.f) ? a0 : 0.01f * a0;
    a1 = (a1 > 0.f) ? a1 : 0.01f * a1;
    float lg[NRELS];
    #pragma unroll
    for (int r = 0; r < NRELS; ++r) {
        float pr = a0 * Wsm_f[r * DD + lane] + a1 * Wsm_f[r * DD + 64 + lane];
        #pragma unroll
        for (int d = 1; d < 64; d <<= 1) pr += __shfl_xor(pr, d, 64);
        lg[r] = pr + bsm_f[r];
    }
    float mx = lg[0];
    #pragma unroll
    for (int r = 1; r < NRELS; ++r) mx = fmaxf(mx, lg[r]);
    float se = 0.f;
    #pragma unroll
    for (int r = 0; r < NRELS; ++r) se += expf(lg[r] - mx);
    float lse = logf(se) + mx;
    if (lane < NRELS) {
        float v = lg[lane] - lse;
        if (detect_bf(wv_raw)) ((__hip_bfloat16*)outp)[p * NRELS + lane] = __float2bfloat16(v);
        else                   ((float*)outp)[p * NRELS + lane] = v;
    }
}

// ---------------------------------------------------------------------------
extern "C" void kernel_launch(void* const* d_in, const int* in_sizes, int n_in,
                              void* d_out, int out_size, void* d_ws, size_t ws_size,
                              hipStream_t stream)
{
    const int* ids = (const int*)d_in[0];

    char* ws = (char*)d_ws;
    f16*   part     = (f16*)ws;                                      // 16 MiB region (f16 partials)
    f16*   h1       = (f16*)(ws + ((size_t)20 << 20));               // 2 MiB
    f16*   h2       = (f16*)(ws + ((size_t)22 << 20));               // 1 MiB
    f16*   h3       = (f16*)(ws + ((size_t)23 << 20));               // 0.5 MiB
    f16*   h4       = (f16*)(ws + ((size_t)23 << 20) + (512 << 10)); // 0.25 MiB
    f16*   WvT      = (f16*)(ws + ((size_t)24 << 20));               // 0.5 MiB
    f16*   Wext     = (f16*)(ws + ((size_t)24 << 20) + (512 << 10)); // 4.0625 MiB
    f16*   Wfin     = Wext + (size_t)NWF;                            // 4.0625 MiB
    float* bias_lvl = (float*)(Wfin + (size_t)NWF);
    float* bias_fin = bias_lvl + 128;
    float* Wsm_f    = bias_fin + 128;
    float* bsm_f    = Wsm_f + NRELS * DD;

    if (ws_size < ((size_t)34 << 20)) return;

    prep_all<<<2145, 256, 0, stream>>>(d_in[1], d_in[2], d_in[3], d_in[4], d_in[5], d_in[6],
                                       d_in[7], d_in[8], d_in[9], d_in[10], d_in[11], d_in[12],
                                       WvT, Wext, Wfin, bias_lvl, bias_fin, Wsm_f, bsm_f);

    // level 1 (fused embed-gather): M=8192, 64 tiles x S=8 x 2 nh -> 1024
    gemm_kernel<<<1024, 128, 0, stream>>>(WvT, ids, Wext, part, 8192, 8, 16);
    epi_level<<<512, 256, 0, stream>>>(part, bias_lvl, h1, 8192, 8);
    // level 2: M=4096, 32 x S=16 x 2 -> 1024
    gemm_kernel<<<1024, 128, 0, stream>>>(h1, nullptr, Wext, part, 4096, 16, 8);
    epi_level<<<256, 256, 0, stream>>>(part, bias_lvl, h2, 4096, 16);
    // level 3: M=2048, 16 x S=32 x 2 -> 1024
    gemm_kernel<<<1024, 128, 0, stream>>>(h2, nullptr, Wext, part, 2048, 32, 4);
    epi_level<<<128, 256, 0, stream>>>(part, bias_lvl, h3, 2048, 32);
    // level 4: M=1024, 8 x S=32 x 2 -> 512
    gemm_kernel<<<512, 128, 0, stream>>>(h3, nullptr, Wext, part, 1024, 32, 4);
    epi_level<<<64, 256, 0, stream>>>(part, bias_lvl, h4, 1024, 32);
    // final: M=512, 4 x S=64 x 2 -> 512
    gemm_kernel<<<512, 128, 0, stream>>>(h4, nullptr, Wfin, part, 512, 64, 2);
    fin_epi<<<128, 256, 0, stream>>>(part, bias_fin, Wsm_f, bsm_f,
                                     (const unsigned short*)d_in[1], d_out, 64);
}

// Round 8
// 270.311 us; speedup vs baseline: 1.2693x; 1.0513x over previous
//
#include <hip/hip_runtime.h>
#include <hip/hip_bf16.h>
#include <hip/hip_fp16.h>

#define DD    128
#define VOCAB 2048
#define NRELS 7
#define NWF   (130 * 16384)   // W frag-layout elements: 128 kron + l + r chunks

typedef _Float16 f16;
typedef __attribute__((ext_vector_type(8))) _Float16 f16x8;
typedef __attribute__((ext_vector_type(4))) float    f32x4;

// flexible-dtype load: bf==1 -> bf16 storage, bf==0 -> f32 storage
__device__ __forceinline__ float lde(const void* p, size_t i, int bf) {
    if (bf) return (float)((const __hip_bfloat16*)p)[i];
    return ((const float*)p)[i];
}

// detect storage dtype by exponent-field sanity of Wv's first 64 uint16s
__device__ __forceinline__ int detect_bf(const unsigned short* wv) {
    int sane = 0;
    #pragma unroll
    for (int i = 0; i < 64; ++i) {
        unsigned e = (wv[i] >> 7) & 0xFFu;
        sane += (e >= 90u && e <= 160u) ? 1 : 0;
    }
    return sane == 64;
}

// ---------------------------------------------------------------------------
// prep_all: one launch does everything.
//  b <  64        : WvT[v][d] = Wv[d][v] + bv[d]  (64x64 LDS transpose tiles)
//  64 <= b < 2144 : W frag-major repack (which, i, n8)
//  b == 2144      : biases + Wsm/bsm f32 copies
// Frag layout: Wf[((i*8+n8)*4+t)*512 + ln*8 + e] =
//              W[n8*16+(ln&15)][i*128 + t*32 + (ln>>4)*8 + e]
// ---------------------------------------------------------------------------
__global__ void prep_all(const void* Wv, const void* bv,
                         const void* Wcps, const void* bcps,
                         const void* Wcpst, const void* bcpst,
                         const void* Wcpr, const void* bcpr,
                         const void* Wcprt, const void* bcprt,
                         const void* Wsm, const void* bsm,
                         f16* __restrict__ WvT, f16* __restrict__ Wext, f16* __restrict__ Wfin,
                         float* __restrict__ bias_lvl, float* __restrict__ bias_fin,
                         float* __restrict__ Wsm_f, float* __restrict__ bsm_f)
{
    const int bf = detect_bf((const unsigned short*)Wv);
    const int b = blockIdx.x;
    const int tid = threadIdx.x;

    if (b < 64) {                     // ---- WvT transpose ----
        __shared__ float tile[64][65];
        int vt = b >> 1, dt = b & 1;
        int tx = tid & 63, ty = tid >> 6;
        for (int yy = ty; yy < 64; yy += 4)
            tile[yy][tx] = lde(Wv, (size_t)(dt * 64 + yy) * VOCAB + vt * 64 + tx, bf);
        __syncthreads();
        for (int yy = ty; yy < 64; yy += 4) {
            int v = vt * 64 + yy, d = dt * 64 + tx;
            WvT[(size_t)v * DD + d] = (f16)(tile[tx][yy] + lde(bv, d, bf));
        }
        return;
    }
    if (b >= 2144) {                  // ---- biases + softmax weights ----
        if (tid < 128)      bias_lvl[tid] = lde(bcps, tid, bf) + lde(bcpst, tid, bf);
        else if (tid < 256) bias_fin[tid - 128] = lde(bcpr, tid - 128, bf) + lde(bcprt, tid - 128, bf);
        for (int o = tid; o < NRELS * DD; o += 256) Wsm_f[o] = lde(Wsm, o, bf);
        if (tid < NRELS) bsm_f[tid] = lde(bsm, tid, bf);
        return;
    }
    // ---- W frag repack ----
    const int bb    = b - 64;
    const int which = bb / 1040;      // 0: ext, 1: fin
    const int rem   = bb - which * 1040;
    const int i     = rem >> 3;       // 0..129
    const int n8    = rem & 7;
    const void* Wt = which ? (const void*)Wcprt : (const void*)Wcpst;
    const void* Ws = which ? (const void*)Wcpr  : (const void*)Wcps;
    f16* dst = which ? Wfin : Wext;

    __shared__ float tile[16 * 129];
    #pragma unroll
    for (int it = 0; it < 8; ++it) {
        int idx = it * 256 + tid;
        int rr = idx >> 7, c = idx & 127;
        float v = (i < 128) ? lde(Wt, (size_t)(n8 * 16 + rr) * 16384 + (size_t)i * 128 + c, bf)
                            : lde(Ws, (size_t)(n8 * 16 + rr) * 256 + (size_t)(i - 128) * 128 + c, bf);
        tile[rr * 129 + c] = v;
    }
    __syncthreads();
    f16* out = dst + (size_t)(i * 8 + n8) * 2048;
    #pragma unroll
    for (int it = 0; it < 8; ++it) {
        int o = it * 256 + tid;
        int t = o >> 9, ln = (o >> 3) & 63, e = o & 7;
        out[o] = (f16)tile[(ln & 15) * 129 + t * 32 + ((ln >> 4) << 3) + e];
    }
}

// ---------------------------------------------------------------------------
// GEMM over A_ext = [kron(l,r) | l | r] vs W (128 x 16640), split-K over kron
// rows i. Block = 128 merge-rows x 64 n (one n-half), 4 waves x 32 rows, all
// reading IDENTICAL W fragments (L1 reuse). 3 waves/SIMD occupancy hides the
// W-load latency that register-ring depth alone couldn't (R5-R7 plateau).
// W prefetch: 2 pair-slots (8 frags each), refilled after pair consumption,
// 2 waits per i-stage, clamped indices (no branches). XCD-pinned n-half.
// If ids != null, gather input rows from hin (=WvT) via leaf ids.
// s==1 appends lin-l (i=128), s==2 lin-r (i=129). Partials f16.
// ---------------------------------------------------------------------------
__launch_bounds__(256, 3)
__global__ void gemm_kernel(const f16* __restrict__ hin, const int* __restrict__ ids,
                            const f16* __restrict__ Wf,
                            f16* __restrict__ part, int Mrows, int S, int BI)
{
    __shared__ f16 Lt[128 * 128];       // 32 KB, phys 8-half block = cb ^ (row&15)

    const int tid  = threadIdx.x;
    const int lane = tid & 63;
    const int wv   = tid >> 6;                     // 0..3
    const int b    = blockIdx.x;
    const int nh   = (b >> 2) & 1;                 // XCD-half -> n-half
    const int r    = ((b >> 3) << 2) | (b & 3);    // 0 .. grid/2-1
    const int mb   = r / S;
    const int s    = r - mb * S;
    const int m0   = mb * 128;
    const int i0   = s * BI;
    const int nI   = BI + ((s == 1 || s == 2) ? 1 : 0);

    // ---- stage Lt (l rows), swizzled 8-half blocks ----
    #pragma unroll
    for (int it = 0; it < 8; ++it) {
        int c  = it * 256 + tid;            // 0..2047
        int mm = c >> 4;                    // 0..127
        int cb = c & 15;
        int row = ids ? ids[2 * (m0 + mm)] : 2 * (m0 + mm);
        f16x8 v = *(const f16x8*)&hin[(size_t)row * DD + cb * 8];
        *(f16x8*)&Lt[mm * 128 + ((cb ^ (mm & 15)) << 3)] = v;
    }

    const int mrow = lane & 15;
    const int q    = lane >> 4;
    const int wm   = wv * 32;

    // ---- r fragments for this wave's 32 rows (reused across all i) ----
    f16x8 rf[2][4];
    #pragma unroll
    for (int mt = 0; mt < 2; ++mt) {
        int p = m0 + wm + mt * 16 + mrow;
        int row = ids ? ids[2 * p + 1] : 2 * p + 1;
        #pragma unroll
        for (int t = 0; t < 4; ++t)
            rf[mt][t] = *(const f16x8*)&hin[(size_t)row * DD + t * 32 + q * 8];
    }

    __syncthreads();

    auto imap = [&](int ii) { return (ii < BI) ? (i0 + ii) : (s == 1 ? 128 : 129); };
    const f16* wb0 = Wf + nh * 8192 + lane * 8;
    auto lpRead = [&](int i, int mt) -> f16 {
        return Lt[(wm + mt * 16 + mrow) * 128 + (((i >> 3) ^ mrow) << 3) + (i & 7)];
    };

    f32x4 acc[2][4] = {};
    f16x8 wA[8], wB[8];                 // 2 pair-slots (t-step pairs)
    f16 lpv[2], lpn[2], lb0[8], lb1[8];

// load the 8 frags of t-step pair P (t = 2P, 2P+1) of kron chunk index ic
#define LDPAIR(ic, P, ARR) {                                                           \
    const f16* _p = wb0 + (size_t)imap(ic) * 16384 + (P) * 1024;                       \
    _Pragma("unroll")                                                                  \
    for (int u = 0; u < 8; ++u)                                                        \
        ARR[u] = *(const f16x8*)(_p + ((u >> 2) * 512) + (u & 3) * 2048);              \
    }

    LDPAIR(0, 0, wA);
    LDPAIR(0, 1, wB);
    {
        int i = imap(0);
        if (i < 128) {
            #pragma unroll
            for (int mt = 0; mt < 2; ++mt) lpv[mt] = lpRead(i, mt);
        }
    }

#define TSTEP(T, ARR, BASE) {                                                           \
    if (i < 128) {                                                                      \
        _Pragma("unroll")                                                               \
        for (int mt = 0; mt < 2; ++mt) {                                                \
            f16x8 a = (mt ? *(f16x8*)lb1 : *(f16x8*)lb0) * rf[mt][T];                   \
            _Pragma("unroll")                                                           \
            for (int nt = 0; nt < 4; ++nt)                                              \
                acc[mt][nt] = __builtin_amdgcn_mfma_f32_16x16x32_f16(a, ARR[(BASE)+nt], acc[mt][nt], 0, 0, 0); \
        }                                                                               \
    } else if (i == 128) {                                                              \
        _Pragma("unroll")                                                               \
        for (int mt = 0; mt < 2; ++mt) {                                                \
            f16x8 a = *(const f16x8*)&Lt[(wm + mt * 16 + mrow) * 128 + ((((T) * 4 + q) ^ mrow) << 3)]; \
            _Pragma("unroll")                                                           \
            for (int nt = 0; nt < 4; ++nt)                                              \
                acc[mt][nt] = __builtin_amdgcn_mfma_f32_16x16x32_f16(a, ARR[(BASE)+nt], acc[mt][nt], 0, 0, 0); \
        }                                                                               \
    } else {                                                                            \
        _Pragma("unroll")                                                               \
        for (int mt = 0; mt < 2; ++mt) {                                                \
            _Pragma("unroll")                                                           \
            for (int nt = 0; nt < 4; ++nt)                                              \
                acc[mt][nt] = __builtin_amdgcn_mfma_f32_16x16x32_f16(rf[mt][T], ARR[(BASE)+nt], acc[mt][nt], 0, 0, 0); \
        }                                                                               \
    } }

    for (int ii = 0; ii < nI; ++ii) {
        const int i   = imap(ii);
        const int iin = (ii + 1 < nI) ? (ii + 1) : (nI - 1);   // clamped prefetch idx
        if (i < 128) {
            #pragma unroll
            for (int e = 0; e < 8; ++e) { lb0[e] = lpv[0]; lb1[e] = lpv[1]; }
        }
        TSTEP(0, wA, 0);
        TSTEP(1, wA, 4);
        LDPAIR(iin, 0, wA);             // refill pair-slot A for next stage
        {
            int i2 = imap(iin);
            if (i2 < 128) {
                #pragma unroll
                for (int mt = 0; mt < 2; ++mt) lpn[mt] = lpRead(i2, mt);
            }
        }
        TSTEP(2, wB, 0);
        TSTEP(3, wB, 4);
        LDPAIR(iin, 1, wB);             // refill pair-slot B for next stage
        #pragma unroll
        for (int mt = 0; mt < 2; ++mt) lpv[mt] = lpn[mt];
    }
#undef TSTEP
#undef LDPAIR

    // ---- store f16 partial tile: C/D layout col=lane&15, row=q*4+reg ----
    f16* pb = part + ((size_t)s * Mrows + m0) * DD + nh * 64;
    #pragma unroll
    for (int mt = 0; mt < 2; ++mt)
        #pragma unroll
        for (int nt = 0; nt < 4; ++nt) {
            int colg = nt * 16 + mrow;
            #pragma unroll
            for (int rr = 0; rr < 4; ++rr) {
                int rowl = wm + mt * 16 + q * 4 + rr;
                pb[(size_t)rowl * DD + colg] = (f16)acc[mt][nt][rr];
            }
        }
}

// ---------------------------------------------------------------------------
// level epilogue: h_out = f16(tanh(sum_s part[s] + bias))
// ---------------------------------------------------------------------------
__global__ void epi_level(const f16* __restrict__ part, const float* __restrict__ bias,
                          f16* __restrict__ hout, int Mrows, int S)
{
    int idx = (blockIdx.x * 256 + threadIdx.x) * 8;
    size_t stride = (size_t)Mrows * DD;
    float sum[8] = {};
    for (int s2 = 0; s2 < S; ++s2) {
        f16x8 v = *(const f16x8*)&part[(size_t)s2 * stride + idx];
        #pragma unroll
        for (int e = 0; e < 8; ++e) sum[e] += (float)v[e];
    }
    int n = idx & 127;
    f16x8 o;
    #pragma unroll
    for (int e = 0; e < 8; ++e) o[e] = (f16)tanhf(sum[e] + bias[n + e]);
    *(f16x8*)&hout[idx] = o;
}

// ---------------------------------------------------------------------------
// final epilogue: leaky_relu(sum_s part + bias) @ Wsm^T + bsm -> log_softmax
// ---------------------------------------------------------------------------
__global__ void fin_epi(const f16* __restrict__ part, const float* __restrict__ bias,
                        const float* __restrict__ Wsm_f, const float* __restrict__ bsm_f,
                        const unsigned short* __restrict__ wv_raw, void* __restrict__ outp, int S)
{
    int lane = threadIdx.x & 63;
    int wv = threadIdx.x >> 6;
    int p = blockIdx.x * 4 + wv;              // 0..511
    size_t stride = (size_t)512 * DD;
    const f16* base = part + (size_t)p * DD;
    float a0 = 0.f, a1 = 0.f;
    for (int s2 = 0; s2 < S; ++s2) {
        a0 += (float)base[(size_t)s2 * stride + lane];
        a1 += (float)base[(size_t)s2 * stride + 64 + lane];
    }
    a0 += bias[lane];      a1 += bias[64 + lane];
    a0 = (a0 > 0.f) ? a0 : 0.01f * a0;
    a1 = (a1 > 0.f) ? a1 : 0.01f * a1;
    float lg[NRELS];
    #pragma unroll
    for (int r = 0; r < NRELS; ++r) {
        float pr = a0 * Wsm_f[r * DD + lane] + a1 * Wsm_f[r * DD + 64 + lane];
        #pragma unroll
        for (int d = 1; d < 64; d <<= 1) pr += __shfl_xor(pr, d, 64);
        lg[r] = pr + bsm_f[r];
    }
    float mx = lg[0];
    #pragma unroll
    for (int r = 1; r < NRELS; ++r) mx = fmaxf(mx, lg[r]);
    float se = 0.f;
    #pragma unroll
    for (int r = 0; r < NRELS; ++r) se += expf(lg[r] - mx);
    float lse = logf(se) + mx;
    if (lane < NRELS) {
        float v = lg[lane] - lse;
        if (detect_bf(wv_raw)) ((__hip_bfloat16*)outp)[p * NRELS + lane] = __float2bfloat16(v);
        else                   ((float*)outp)[p * NRELS + lane] = v;
    }
}

// ---------------------------------------------------------------------------
extern "C" void kernel_launch(void* const* d_in, const int* in_sizes, int n_in,
                              void* d_out, int out_size, void* d_ws, size_t ws_size,
                              hipStream_t stream)
{
    const int* ids = (const int*)d_in[0];

    char* ws = (char*)d_ws;
    f16*   part     = (f16*)ws;                                      // 16 MiB region (f16 partials)
    f16*   h1       = (f16*)(ws + ((size_t)20 << 20));               // 2 MiB
    f16*   h2       = (f16*)(ws + ((size_t)22 << 20));               // 1 MiB
    f16*   h3       = (f16*)(ws + ((size_t)23 << 20));               // 0.5 MiB
    f16*   h4       = (f16*)(ws + ((size_t)23 << 20) + (512 << 10)); // 0.25 MiB
    f16*   WvT      = (f16*)(ws + ((size_t)24 << 20));               // 0.5 MiB
    f16*   Wext     = (f16*)(ws + ((size_t)24 << 20) + (512 << 10)); // 4.0625 MiB
    f16*   Wfin     = Wext + (size_t)NWF;                            // 4.0625 MiB
    float* bias_lvl = (float*)(Wfin + (size_t)NWF);
    float* bias_fin = bias_lvl + 128;
    float* Wsm_f    = bias_fin + 128;
    float* bsm_f    = Wsm_f + NRELS * DD;

    if (ws_size < ((size_t)34 << 20)) return;

    prep_all<<<2145, 256, 0, stream>>>(d_in[1], d_in[2], d_in[3], d_in[4], d_in[5], d_in[6],
                                       d_in[7], d_in[8], d_in[9], d_in[10], d_in[11], d_in[12],
                                       WvT, Wext, Wfin, bias_lvl, bias_fin, Wsm_f, bsm_f);

    // level 1 (fused embed-gather): M=8192, 64 mtiles x S=8 x 2 nh -> 1024
    gemm_kernel<<<1024, 256, 0, stream>>>(WvT, ids, Wext, part, 8192, 8, 16);
    epi_level<<<512, 256, 0, stream>>>(part, bias_lvl, h1, 8192, 8);
    // level 2: M=4096, 32 mtiles x S=8 x 2 -> 512, nI=16/17
    gemm_kernel<<<512, 256, 0, stream>>>(h1, nullptr, Wext, part, 4096, 8, 16);
    epi_level<<<256, 256, 0, stream>>>(part, bias_lvl, h2, 4096, 8);
    // level 3: M=2048, 16 mtiles x S=16 x 2 -> 512, nI=8/9
    gemm_kernel<<<512, 256, 0, stream>>>(h2, nullptr, Wext, part, 2048, 16, 8);
    epi_level<<<128, 256, 0, stream>>>(part, bias_lvl, h3, 2048, 16);
    // level 4: M=1024, 8 mtiles x S=16 x 2 -> 256, nI=8/9
    gemm_kernel<<<256, 256, 0, stream>>>(h3, nullptr, Wext, part, 1024, 16, 8);
    epi_level<<<64, 256, 0, stream>>>(part, bias_lvl, h4, 1024, 16);
    // final: M=512, 4 mtiles x S=32 x 2 -> 256, nI=4/5
    gemm_kernel<<<256, 256, 0, stream>>>(h4, nullptr, Wfin, part, 512, 32, 4);
    fin_epi<<<128, 256, 0, stream>>>(part, bias_fin, Wsm_f, bsm_f,
                                     (const unsigned short*)d_in[1], d_out, 32);
}